// Round 1
// baseline (313.874 us; speedup 1.0000x reference)
//
#include <hip/hip_runtime.h>
#include <cstdint>
#include <cstddef>

// GCN link prediction forward:
//   Y1 = x@W1; H = relu(adj@Y1 + b1); Y2 = H@W2; Z = adj@Y2 + b2; out = sigmoid(Z@Z^T)
// All GEMMs run as bf16 MFMA (f32 accum) in "BT" form: C[m][n] = sum_k A[m][k]*BT[n][k].
// Intermediates are produced pre-transposed so every B-operand is [N][K] row-major.
// adj (bf16) is staged in d_out[0..128MB) — dead by the time gemm5 overwrites d_out.

typedef unsigned short u16;
typedef __attribute__((ext_vector_type(8))) short short8;   // 8 bf16 = 4 VGPR (MFMA A/B frag)
typedef __attribute__((ext_vector_type(4))) float f32x4;    // MFMA C/D frag
typedef __attribute__((ext_vector_type(8))) unsigned short ushort8;

__device__ __forceinline__ u16 f2bf(float v) {
    union { float f; unsigned int u; } c; c.f = v;
    unsigned int r = c.u + 0x7FFFu + ((c.u >> 16) & 1u);   // RNE
    return (u16)(r >> 16);
}

__device__ __forceinline__ void gload16(const void* g, void* l) {
    auto gp = (const __attribute__((address_space(1))) void*)(
        reinterpret_cast<uintptr_t>(g));
    auto lp = (__attribute__((address_space(3))) void*)(
        reinterpret_cast<uintptr_t>(l));
    __builtin_amdgcn_global_load_lds(gp, lp, 16, 0, 0);
}

// ---------------------------------------------------------------------------
// Templated bf16 BT-GEMM. BK=64, MFMA 16x16x32.
// EPI: 0 = store bf16 ; 1 = relu(v+bias[col]) bf16 ; 3 = store f32 partial
//      (offset blockIdx.z*M*ldc) ; 4 = sigmoid -> f32
// ---------------------------------------------------------------------------
template <int BM, int BN, int WM, int WN, int EPI>
__launch_bounds__((BM / WM) * (BN / WN) * 64, 2)
__global__ void gemm_bt(const u16* __restrict__ A, int lda,
                        const u16* __restrict__ B, int ldb,
                        void* __restrict__ C, int ldc,
                        const float* __restrict__ bias,
                        int M, int N, int kLen) {
    constexpr int BK = 64;
    constexpr int NWCOL = BN / WN;
    constexpr int NWAVES = (BM / WM) * (BN / WN);
    constexpr int THREADS = NWAVES * 64;
    constexpr int MI = WM / 16, NI = WN / 16;
    constexpr int A_LOADS = (BM * BK * 2) / (THREADS * 16);
    constexpr int B_LOADS = (BN * BK * 2) / (THREADS * 16);

    __shared__ u16 Al[2][BM * BK];
    __shared__ u16 Bl[2][BN * BK];

    const int tid = threadIdx.x;
    const int m0 = blockIdx.y * BM;
    const int n0 = blockIdx.x * BN;
    const int kbase = blockIdx.z * kLen;

    const int l = tid & 63;
    const int w = tid >> 6;
    const int wr = w / NWCOL, wc = w % NWCOL;
    const int lr = l & 15, lk = l >> 4;

    const size_t ldab = (size_t)lda * 2, ldbb = (size_t)ldb * 2;
    const char* Abase = (const char*)(A + (size_t)m0 * lda + kbase);
    const char* Bbase = (const char*)(B + (size_t)n0 * ldb + kbase);

    auto stage = [&](int buf, int kt) {
        const char* a = Abase + (size_t)kt * (BK * 2);
        const char* b = Bbase + (size_t)kt * (BK * 2);
#pragma unroll
        for (int i = 0; i < A_LOADS; i++) {
            int off = (tid + i * THREADS) * 16;
            gload16(a + (size_t)(off >> 7) * ldab + (off & 127),
                    (char*)&Al[buf][0] + off);
        }
#pragma unroll
        for (int i = 0; i < B_LOADS; i++) {
            int off = (tid + i * THREADS) * 16;
            gload16(b + (size_t)(off >> 7) * ldbb + (off & 127),
                    (char*)&Bl[buf][0] + off);
        }
    };

    f32x4 acc[MI][NI] = {};

    const int ksteps = kLen / BK;
    stage(0, 0);
    for (int kt = 0; kt < ksteps; ++kt) {
        const int cur = kt & 1;
        __syncthreads();   // staging(cur) complete; previous readers of cur done
        if (kt + 1 < ksteps) stage(cur ^ 1, kt + 1);
#pragma unroll
        for (int ks = 0; ks < 2; ++ks) {
            short8 af[MI];
            short8 bf[NI];
#pragma unroll
            for (int mi = 0; mi < MI; ++mi)
                af[mi] = *(const short8*)&Al[cur][(wr * WM + mi * 16 + lr) * BK + ks * 32 + lk * 8];
#pragma unroll
            for (int ni = 0; ni < NI; ++ni)
                bf[ni] = *(const short8*)&Bl[cur][(wc * WN + ni * 16 + lr) * BK + ks * 32 + lk * 8];
#pragma unroll
            for (int mi = 0; mi < MI; ++mi)
#pragma unroll
                for (int ni = 0; ni < NI; ++ni)
                    acc[mi][ni] = __builtin_amdgcn_mfma_f32_16x16x32_bf16(
                        af[mi], bf[ni], acc[mi][ni], 0, 0, 0);
        }
    }

    // epilogue: C/D frag mapping col=lane&15, row=(lane>>4)*4+r  [m89-verified]
#pragma unroll
    for (int mi = 0; mi < MI; ++mi) {
#pragma unroll
        for (int ni = 0; ni < NI; ++ni) {
            const int row = m0 + wr * WM + mi * 16 + lk * 4;
            const int col = n0 + wc * WN + ni * 16 + lr;
            f32x4 v = acc[mi][ni];
            if constexpr (EPI == 0) {
                u16* Cp = (u16*)C;
#pragma unroll
                for (int r = 0; r < 4; r++)
                    Cp[(size_t)(row + r) * ldc + col] = f2bf(v[r]);
            } else if constexpr (EPI == 1) {
                const float bb = bias[col];
                u16* Cp = (u16*)C;
#pragma unroll
                for (int r = 0; r < 4; r++) {
                    float x = v[r] + bb;
                    x = x > 0.f ? x : 0.f;
                    Cp[(size_t)(row + r) * ldc + col] = f2bf(x);
                }
            } else if constexpr (EPI == 3) {
                float* Cp = (float*)C + (size_t)blockIdx.z * M * ldc;
#pragma unroll
                for (int r = 0; r < 4; r++)
                    Cp[(size_t)(row + r) * ldc + col] = v[r];
            } else if constexpr (EPI == 4) {
                float* Cp = (float*)C;
#pragma unroll
                for (int r = 0; r < 4; r++) {
                    float s = 1.0f / (1.0f + __expf(-v[r]));
                    Cp[(size_t)(row + r) * ldc + col] = s;
                }
            }
        }
    }
}

// ---------------------------------------------------------------------------
// f32 -> bf16 conversion, 8 elements/thread/iter (32B read, 16B write)
// ---------------------------------------------------------------------------
__global__ void cvt8(const float* __restrict__ in, u16* __restrict__ out, int n8) {
    int stride = gridDim.x * blockDim.x;
    for (int i = blockIdx.x * blockDim.x + threadIdx.x; i < n8; i += stride) {
        f32x4 a = ((const f32x4*)in)[2 * (size_t)i];
        f32x4 b = ((const f32x4*)in)[2 * (size_t)i + 1];
        ushort8 o;
        o[0] = f2bf(a[0]); o[1] = f2bf(a[1]); o[2] = f2bf(a[2]); o[3] = f2bf(a[3]);
        o[4] = f2bf(b[0]); o[5] = f2bf(b[1]); o[6] = f2bf(b[2]); o[7] = f2bf(b[3]);
        ((ushort8*)out)[i] = o;
    }
}

// transpose + convert: in[R][C] f32 -> out[C][R] bf16 (tiny weight matrices)
__global__ void trcvt(const float* __restrict__ in, u16* __restrict__ out, int R, int C) {
    int i = blockIdx.x * blockDim.x + threadIdx.x;
    if (i < R * C) {
        int r = i / C, c = i - r * C;
        out[(size_t)c * R + r] = f2bf(in[i]);
    }
}

// Z = partial0 + partial1 + b2  (split-K reduce), -> bf16
__global__ void reduce_z(const float* __restrict__ p, const float* __restrict__ b2,
                         u16* __restrict__ zb, int n) {
    int i = blockIdx.x * blockDim.x + threadIdx.x;
    if (i < n) zb[i] = f2bf(p[i] + p[i + n] + b2[i & 63]);
}

// ---------------------------------------------------------------------------
extern "C" void kernel_launch(void* const* d_in, const int* in_sizes, int n_in,
                              void* d_out, int out_size, void* d_ws, size_t ws_size,
                              hipStream_t stream) {
    constexpr int N = 8192, F = 512, H = 256, CL = 64;

    const float* x   = (const float*)d_in[0];
    const float* adj = (const float*)d_in[1];
    const float* W1  = (const float*)d_in[2];
    const float* b1  = (const float*)d_in[3];
    const float* W2  = (const float*)d_in[4];
    const float* b2  = (const float*)d_in[5];
    float* out = (float*)d_out;

    // adj bf16 lives in d_out (128MB of 256MB); dead before gemm5 overwrites.
    u16* adjb = (u16*)d_out;

    // workspace carve-up (~23.4 MB total)
    u16* xb   = (u16*)d_ws;                       // [8192][512]
    u16* W1tb = xb   + (size_t)N * F;             // [256][512]
    u16* Y1tb = W1tb + (size_t)H * F;             // [256][8192]
    u16* Hb   = Y1tb + (size_t)H * N;             // [8192][256]
    u16* W2tb = Hb   + (size_t)N * H;             // [64][256]
    u16* Y2tb = W2tb + (size_t)CL * H;            // [64][8192]
    u16* Zb   = Y2tb + (size_t)CL * N;            // [8192][64]
    float* Zp = (float*)(Zb + (size_t)N * CL);    // [2][8192][64] f32 partials

    // conversions
    cvt8<<<2048, 256, 0, stream>>>(adj, adjb, N * N / 8);
    cvt8<<<2048, 256, 0, stream>>>(x, xb, N * F / 8);
    trcvt<<<(F * H + 255) / 256, 256, 0, stream>>>(W1, W1tb, F, H);
    trcvt<<<(H * CL + 255) / 256, 256, 0, stream>>>(W2, W2tb, H, CL);

    // gemm1: Y1t[h][m] = sum_k W1t[h][k] * x[m][k]   (M=256, N=8192, K=512)
    gemm_bt<64, 64, 32, 32, 0><<<dim3(N / 64, H / 64, 1), 256, 0, stream>>>(
        W1tb, F, xb, F, Y1tb, N, nullptr, H, N, F);

    // gemm2: H[m][h] = relu(sum_k adj[m][k] * Y1t[h][k] + b1[h])  (M=8192, N=256, K=8192)
    gemm_bt<64, 64, 32, 32, 1><<<dim3(H / 64, N / 64, 1), 256, 0, stream>>>(
        adjb, N, Y1tb, N, Hb, H, b1, N, H, N);

    // gemm3: Y2t[c][m] = sum_k W2t[c][k] * H[m][k]   (M=64, N=8192, K=256)
    gemm_bt<64, 64, 32, 32, 0><<<dim3(N / 64, 1, 1), 256, 0, stream>>>(
        W2tb, H, Hb, H, Y2tb, N, nullptr, CL, N, H);

    // gemm4 (split-K=2): Zp[z][m][c] = sum_{k in half z} adj[m][k] * Y2t[c][k]
    gemm_bt<64, 64, 32, 32, 3><<<dim3(1, N / 64, 2), 256, 0, stream>>>(
        adjb, N, Y2tb, N, Zp, CL, nullptr, N, CL, N / 2);

    // Zb = bf16(Zp0 + Zp1 + b2)
    reduce_z<<<(N * CL) / 256, 256, 0, stream>>>(Zp, b2, Zb, N * CL);

    // gemm5: out[i][j] = sigmoid(sum_k Zb[i][k] * Zb[j][k])  (M=N=8192, K=64)
    gemm_bt<128, 128, 64, 64, 4><<<dim3(N / 128, N / 128, 1), 256, 0, stream>>>(
        Zb, CL, Zb, CL, out, N, nullptr, N, N, CL);
}

// Round 3
// 263.215 us; speedup vs baseline: 1.1925x; 1.1925x over previous
//
#include <hip/hip_runtime.h>
#include <cstdint>
#include <cstddef>

// GCN link prediction forward:
//   Y1 = x@W1; H = relu(adj@Y1 + b1); Y2 = H@W2; Z = adj@Y2 + b2; out = sigmoid(Z@Z^T)
// All GEMMs run as bf16 MFMA (f32 accum) in "BT" form: C[m][n] = sum_k A[m][k]*BT[n][k].
// Intermediates are produced pre-transposed so every B-operand is [N][K] row-major.
// d_out carve (dead until gemm5 overwrites all 256 MiB):
//   [0,128M)    adj bf16
//   [128M,144M) Hp: f32 split-K partials of gemm2   [2][8192][256]
//   [144M,152M) Zp: f32 split-K partials of gemm4   [4][8192][64]

typedef unsigned short u16;
typedef __attribute__((ext_vector_type(8))) short short8;   // 8 bf16 = 4 VGPR (MFMA A/B frag)
typedef __attribute__((ext_vector_type(4))) float f32x4;    // MFMA C/D frag
typedef __attribute__((ext_vector_type(8))) unsigned short ushort8;
typedef __attribute__((ext_vector_type(4))) unsigned short u16x4;

__device__ __forceinline__ u16 f2bf(float v) {
    union { float f; unsigned int u; } c; c.f = v;
    unsigned int r = c.u + 0x7FFFu + ((c.u >> 16) & 1u);   // RNE
    return (u16)(r >> 16);
}

__device__ __forceinline__ void gload16(const void* g, void* l) {
    auto gp = (const __attribute__((address_space(1))) void*)(
        reinterpret_cast<uintptr_t>(g));
    auto lp = (__attribute__((address_space(3))) void*)(
        reinterpret_cast<uintptr_t>(l));
    __builtin_amdgcn_global_load_lds(gp, lp, 16, 0, 0);
}

// ---------------------------------------------------------------------------
// Templated bf16 BT-GEMM. BK=64, MFMA 16x16x32.
// EPI: 0 = store bf16 ; 1 = relu(v+bias[col]) bf16 ; 3 = store f32 partial
//      (offset blockIdx.z*M*ldc) ; 4 = sigmoid -> f32
// ---------------------------------------------------------------------------
template <int BM, int BN, int WM, int WN, int EPI>
__launch_bounds__((BM / WM) * (BN / WN) * 64, 2)
__global__ void gemm_bt(const u16* __restrict__ A, int lda,
                        const u16* __restrict__ B, int ldb,
                        void* __restrict__ C, int ldc,
                        const float* __restrict__ bias,
                        int M, int N, int kLen) {
    constexpr int BK = 64;
    constexpr int NWCOL = BN / WN;
    constexpr int NWAVES = (BM / WM) * (BN / WN);
    constexpr int THREADS = NWAVES * 64;
    constexpr int MI = WM / 16, NI = WN / 16;
    constexpr int A_LOADS = (BM * BK * 2) / (THREADS * 16);
    constexpr int B_LOADS = (BN * BK * 2) / (THREADS * 16);

    __shared__ u16 Al[2][BM * BK];
    __shared__ u16 Bl[2][BN * BK];

    const int tid = threadIdx.x;
    const int m0 = blockIdx.y * BM;
    const int n0 = blockIdx.x * BN;
    const int kbase = blockIdx.z * kLen;

    const int l = tid & 63;
    const int w = tid >> 6;
    const int wr = w / NWCOL, wc = w % NWCOL;
    const int lr = l & 15, lk = l >> 4;

    const size_t ldab = (size_t)lda * 2, ldbb = (size_t)ldb * 2;
    const char* Abase = (const char*)(A + (size_t)m0 * lda + kbase);
    const char* Bbase = (const char*)(B + (size_t)n0 * ldb + kbase);

    auto stage = [&](int buf, int kt) {
        const char* a = Abase + (size_t)kt * (BK * 2);
        const char* b = Bbase + (size_t)kt * (BK * 2);
#pragma unroll
        for (int i = 0; i < A_LOADS; i++) {
            int off = (tid + i * THREADS) * 16;
            gload16(a + (size_t)(off >> 7) * ldab + (off & 127),
                    (char*)&Al[buf][0] + off);
        }
#pragma unroll
        for (int i = 0; i < B_LOADS; i++) {
            int off = (tid + i * THREADS) * 16;
            gload16(b + (size_t)(off >> 7) * ldbb + (off & 127),
                    (char*)&Bl[buf][0] + off);
        }
    };

    f32x4 acc[MI][NI] = {};

    const int ksteps = kLen / BK;
    stage(0, 0);
    for (int kt = 0; kt < ksteps; ++kt) {
        const int cur = kt & 1;
        __syncthreads();   // staging(cur) complete; previous readers of cur done
        if (kt + 1 < ksteps) stage(cur ^ 1, kt + 1);
#pragma unroll
        for (int ks = 0; ks < 2; ++ks) {
            short8 af[MI];
            short8 bf[NI];
#pragma unroll
            for (int mi = 0; mi < MI; ++mi)
                af[mi] = *(const short8*)&Al[cur][(wr * WM + mi * 16 + lr) * BK + ks * 32 + lk * 8];
#pragma unroll
            for (int ni = 0; ni < NI; ++ni)
                bf[ni] = *(const short8*)&Bl[cur][(wc * WN + ni * 16 + lr) * BK + ks * 32 + lk * 8];
#pragma unroll
            for (int mi = 0; mi < MI; ++mi)
#pragma unroll
                for (int ni = 0; ni < NI; ++ni)
                    acc[mi][ni] = __builtin_amdgcn_mfma_f32_16x16x32_bf16(
                        af[mi], bf[ni], acc[mi][ni], 0, 0, 0);
        }
    }

    // epilogue: C/D frag mapping col=lane&15, row=(lane>>4)*4+r  [m89-verified]
#pragma unroll
    for (int mi = 0; mi < MI; ++mi) {
#pragma unroll
        for (int ni = 0; ni < NI; ++ni) {
            const int row = m0 + wr * WM + mi * 16 + lk * 4;
            const int col = n0 + wc * WN + ni * 16 + lr;
            f32x4 v = acc[mi][ni];
            if constexpr (EPI == 0) {
                u16* Cp = (u16*)C;
#pragma unroll
                for (int r = 0; r < 4; r++)
                    Cp[(size_t)(row + r) * ldc + col] = f2bf(v[r]);
            } else if constexpr (EPI == 1) {
                const float bb = bias[col];
                u16* Cp = (u16*)C;
#pragma unroll
                for (int r = 0; r < 4; r++) {
                    float x = v[r] + bb;
                    x = x > 0.f ? x : 0.f;
                    Cp[(size_t)(row + r) * ldc + col] = f2bf(x);
                }
            } else if constexpr (EPI == 3) {
                float* Cp = (float*)C + (size_t)blockIdx.z * M * ldc;
#pragma unroll
                for (int r = 0; r < 4; r++)
                    Cp[(size_t)(row + r) * ldc + col] = v[r];
            } else if constexpr (EPI == 4) {
                float* Cp = (float*)C;
#pragma unroll
                for (int r = 0; r < 4; r++) {
                    float s = 1.0f / (1.0f + __expf(-v[r]));
                    Cp[(size_t)(row + r) * ldc + col] = s;
                }
            }
        }
    }
}

// ---------------------------------------------------------------------------
// f32 -> bf16 conversion, 8 elements/thread/iter (32B read, 16B write)
// ---------------------------------------------------------------------------
__global__ void cvt8(const float* __restrict__ in, u16* __restrict__ out, int n8) {
    int stride = gridDim.x * blockDim.x;
    for (int i = blockIdx.x * blockDim.x + threadIdx.x; i < n8; i += stride) {
        f32x4 a = ((const f32x4*)in)[2 * (size_t)i];
        f32x4 b = ((const f32x4*)in)[2 * (size_t)i + 1];
        ushort8 o;
        o[0] = f2bf(a[0]); o[1] = f2bf(a[1]); o[2] = f2bf(a[2]); o[3] = f2bf(a[3]);
        o[4] = f2bf(b[0]); o[5] = f2bf(b[1]); o[6] = f2bf(b[2]); o[7] = f2bf(b[3]);
        ((ushort8*)out)[i] = o;
    }
}

// transpose + convert: in[R][C] f32 -> out[C][R] bf16 (tiny weight matrices)
__global__ void trcvt(const float* __restrict__ in, u16* __restrict__ out, int R, int C) {
    int i = blockIdx.x * blockDim.x + threadIdx.x;
    if (i < R * C) {
        int r = i / C, c = i - r * C;
        out[(size_t)c * R + r] = f2bf(in[i]);
    }
}

// split-K reduce: out[i] = bf16( [relu]( sum_z p[z][i] + bias[i & colmask] ) )
// vectorized 4 elements/thread
template <int PARTS, bool RELU>
__global__ void reduce_add(const float* __restrict__ p, const float* __restrict__ bias,
                           u16* __restrict__ out, int n, int colmask) {
    int i = (blockIdx.x * blockDim.x + threadIdx.x) * 4;
    if (i >= n) return;
    f32x4 acc = *(const f32x4*)(p + i);
#pragma unroll
    for (int z = 1; z < PARTS; z++) {
        f32x4 q = *(const f32x4*)(p + (size_t)z * n + i);
        acc[0] += q[0]; acc[1] += q[1]; acc[2] += q[2]; acc[3] += q[3];
    }
    u16x4 o;
#pragma unroll
    for (int j = 0; j < 4; j++) {
        float v = acc[j] + bias[(i + j) & colmask];
        if constexpr (RELU) v = v > 0.f ? v : 0.f;
        o[j] = f2bf(v);
    }
    *(u16x4*)(out + i) = o;
}

// ---------------------------------------------------------------------------
extern "C" void kernel_launch(void* const* d_in, const int* in_sizes, int n_in,
                              void* d_out, int out_size, void* d_ws, size_t ws_size,
                              hipStream_t stream) {
    constexpr int N = 8192, F = 512, H = 256, CL = 64;

    const float* x   = (const float*)d_in[0];
    const float* adj = (const float*)d_in[1];
    const float* W1  = (const float*)d_in[2];
    const float* b1  = (const float*)d_in[3];
    const float* W2  = (const float*)d_in[4];
    const float* b2  = (const float*)d_in[5];
    float* out = (float*)d_out;

    // d_out carve (all dead before gemm5 overwrites the full 256 MiB)
    u16*   adjb = (u16*)d_out;                                        // 128 MiB
    float* Hp   = (float*)((char*)d_out + (size_t)128 * 1024 * 1024); // 16 MiB: [2][8192][256]
    float* Zp   = (float*)((char*)d_out + (size_t)144 * 1024 * 1024); // 8 MiB:  [4][8192][64]

    // workspace carve-up (~18.3 MB total)
    u16* xb   = (u16*)d_ws;                       // [8192][512]
    u16* W1tb = xb   + (size_t)N * F;             // [256][512]
    u16* Y1tb = W1tb + (size_t)H * F;             // [256][8192]
    u16* Hb   = Y1tb + (size_t)H * N;             // [8192][256]
    u16* W2tb = Hb   + (size_t)N * H;             // [64][256]
    u16* Y2tb = W2tb + (size_t)CL * H;            // [64][8192]
    u16* Zb   = Y2tb + (size_t)CL * N;            // [8192][64]

    // conversions
    cvt8<<<2048, 256, 0, stream>>>(adj, adjb, N * N / 8);
    cvt8<<<2048, 256, 0, stream>>>(x, xb, N * F / 8);
    trcvt<<<(F * H + 255) / 256, 256, 0, stream>>>(W1, W1tb, F, H);
    trcvt<<<(H * CL + 255) / 256, 256, 0, stream>>>(W2, W2tb, H, CL);

    // gemm1: Y1t[h][m] = sum_k W1t[h][k] * x[m][k]   (M=256, N=8192, K=512)
    gemm_bt<64, 128, 32, 64, 0><<<dim3(N / 128, H / 64, 1), 256, 0, stream>>>(
        W1tb, F, xb, F, Y1tb, N, nullptr, H, N, F);

    // gemm2 (split-K=2): Hp[z][m][h] = sum_{k in half z} adj[m][k] * Y1t[h][k]
    //   (M=8192, N=256, K=8192)
    gemm_bt<128, 128, 64, 64, 3><<<dim3(H / 128, N / 128, 2), 256, 0, stream>>>(
        adjb, N, Y1tb, N, Hp, H, nullptr, N, H, N / 2);

    // Hb = bf16(relu(Hp0 + Hp1 + b1))
    reduce_add<2, true><<<(N * H / 4 + 255) / 256, 256, 0, stream>>>(
        Hp, b1, Hb, N * H, H - 1);

    // gemm3: Y2t[c][m] = sum_k W2t[c][k] * H[m][k]   (M=64, N=8192, K=256)
    gemm_bt<64, 64, 32, 32, 0><<<dim3(N / 64, 1, 1), 256, 0, stream>>>(
        W2tb, H, Hb, H, Y2tb, N, nullptr, CL, N, H);

    // gemm4 (split-K=4): Zp[z][m][c] = sum_{k in quarter z} adj[m][k] * Y2t[c][k]
    gemm_bt<128, 64, 64, 32, 3><<<dim3(1, N / 128, 4), 256, 0, stream>>>(
        adjb, N, Y2tb, N, Zp, CL, nullptr, N, CL, N / 4);

    // Zb = bf16(Zp0+Zp1+Zp2+Zp3 + b2)
    reduce_add<4, false><<<(N * CL / 4 + 255) / 256, 256, 0, stream>>>(
        Zp, b2, Zb, N * CL, CL - 1);

    // gemm5: out[i][j] = sigmoid(sum_k Zb[i][k] * Zb[j][k])  (M=N=8192, K=64)
    gemm_bt<128, 128, 64, 64, 4><<<dim3(N / 128, N / 128, 1), 256, 0, stream>>>(
        Zb, CL, Zb, CL, out, N, nullptr, N, N, CL);
}

// Round 4
// 244.694 us; speedup vs baseline: 1.2827x; 1.0757x over previous
//
#include <hip/hip_runtime.h>
#include <cstdint>
#include <cstddef>

// GCN link prediction forward:
//   Y1 = x@W1; H = relu(adj@Y1 + b1); Y2 = H@W2; Z = adj@Y2 + b2; out = sigmoid(Z@Z^T)
// All GEMMs: bf16 MFMA (f32 accum), BT form: C[m][n] = sum_k A[m][k]*BT[n][k].
// adj is consumed in f32 by gemm2 (fused cvt in A-staging); gemm2 side-stores
// bf16 adj into d_out for gemm4.
// d_out carve (dead until gemm5 overwrites all 256 MiB at the end):
//   [0,128M)    adjb bf16 [8192][8192]          (written by gemm2, read by gemm4)
//   [128M,160M) Hp: f32 partials of gemm2       [4][8192][256]
//   [160M,176M) Zp: f32 partials of gemm4       [8][8192][64]

typedef unsigned short u16;
typedef __attribute__((ext_vector_type(8))) short short8;   // 8 bf16 (MFMA A/B frag)
typedef __attribute__((ext_vector_type(4))) float f32x4;    // MFMA C/D frag
typedef __attribute__((ext_vector_type(8))) unsigned short ushort8;
typedef __attribute__((ext_vector_type(4))) unsigned short u16x4;

__device__ __forceinline__ u16 f2bf(float v) {
    union { float f; unsigned int u; } c; c.f = v;
    unsigned int r = c.u + 0x7FFFu + ((c.u >> 16) & 1u);   // RNE
    return (u16)(r >> 16);
}

__device__ __forceinline__ void gload16(const void* g, void* l) {
    auto gp = (const __attribute__((address_space(1))) void*)(
        reinterpret_cast<uintptr_t>(g));
    auto lp = (__attribute__((address_space(3))) void*)(
        reinterpret_cast<uintptr_t>(l));
    __builtin_amdgcn_global_load_lds(gp, lp, 16, 0, 0);
}

// ---------------------------------------------------------------------------
// Templated bf16 BT-GEMM (both operands already bf16). BK=64, MFMA 16x16x32.
// EPI: 0 = store bf16 ; 3 = f32 partial at blockIdx.z*M*ldc ; 4 = sigmoid f32
// ---------------------------------------------------------------------------
template <int BM, int BN, int WM, int WN, int EPI>
__launch_bounds__((BM / WM) * (BN / WN) * 64, 2)
__global__ void gemm_bt(const u16* __restrict__ A, int lda,
                        const u16* __restrict__ B, int ldb,
                        void* __restrict__ C, int ldc,
                        const float* __restrict__ bias,
                        int M, int N, int kLen) {
    constexpr int BK = 64;
    constexpr int NWCOL = BN / WN;
    constexpr int NWAVES = (BM / WM) * (BN / WN);
    constexpr int THREADS = NWAVES * 64;
    constexpr int MI = WM / 16, NI = WN / 16;
    constexpr int A_LOADS = (BM * BK * 2) / (THREADS * 16);
    constexpr int B_LOADS = (BN * BK * 2) / (THREADS * 16);

    __shared__ u16 Al[2][BM * BK];
    __shared__ u16 Bl[2][BN * BK];

    const int tid = threadIdx.x;
    const int m0 = blockIdx.y * BM;
    const int n0 = blockIdx.x * BN;
    const int kbase = blockIdx.z * kLen;

    const int l = tid & 63;
    const int w = tid >> 6;
    const int wr = w / NWCOL, wc = w % NWCOL;
    const int lr = l & 15, lk = l >> 4;

    const size_t ldab = (size_t)lda * 2, ldbb = (size_t)ldb * 2;
    const char* Abase = (const char*)(A + (size_t)m0 * lda + kbase);
    const char* Bbase = (const char*)(B + (size_t)n0 * ldb + kbase);

    auto stage = [&](int buf, int kt) {
        const char* a = Abase + (size_t)kt * (BK * 2);
        const char* b = Bbase + (size_t)kt * (BK * 2);
#pragma unroll
        for (int i = 0; i < A_LOADS; i++) {
            int off = (tid + i * THREADS) * 16;
            gload16(a + (size_t)(off >> 7) * ldab + (off & 127),
                    (char*)&Al[buf][0] + off);
        }
#pragma unroll
        for (int i = 0; i < B_LOADS; i++) {
            int off = (tid + i * THREADS) * 16;
            gload16(b + (size_t)(off >> 7) * ldbb + (off & 127),
                    (char*)&Bl[buf][0] + off);
        }
    };

    f32x4 acc[MI][NI] = {};

    const int ksteps = kLen / BK;
    stage(0, 0);
    for (int kt = 0; kt < ksteps; ++kt) {
        const int cur = kt & 1;
        __syncthreads();
        if (kt + 1 < ksteps) stage(cur ^ 1, kt + 1);
#pragma unroll
        for (int ks = 0; ks < 2; ++ks) {
            short8 af[MI];
            short8 bf[NI];
#pragma unroll
            for (int mi = 0; mi < MI; ++mi)
                af[mi] = *(const short8*)&Al[cur][(wr * WM + mi * 16 + lr) * BK + ks * 32 + lk * 8];
#pragma unroll
            for (int ni = 0; ni < NI; ++ni)
                bf[ni] = *(const short8*)&Bl[cur][(wc * WN + ni * 16 + lr) * BK + ks * 32 + lk * 8];
#pragma unroll
            for (int mi = 0; mi < MI; ++mi)
#pragma unroll
                for (int ni = 0; ni < NI; ++ni)
                    acc[mi][ni] = __builtin_amdgcn_mfma_f32_16x16x32_bf16(
                        af[mi], bf[ni], acc[mi][ni], 0, 0, 0);
        }
    }

    // epilogue: C/D frag mapping col=lane&15, row=(lane>>4)*4+r  [m89-verified]
#pragma unroll
    for (int mi = 0; mi < MI; ++mi) {
#pragma unroll
        for (int ni = 0; ni < NI; ++ni) {
            const int row = m0 + wr * WM + mi * 16 + lk * 4;
            const int col = n0 + wc * WN + ni * 16 + lr;
            f32x4 v = acc[mi][ni];
            if constexpr (EPI == 0) {
                u16* Cp = (u16*)C;
#pragma unroll
                for (int r = 0; r < 4; r++)
                    Cp[(size_t)(row + r) * ldc + col] = f2bf(v[r]);
            } else if constexpr (EPI == 3) {
                float* Cp = (float*)C + (size_t)blockIdx.z * M * ldc;
#pragma unroll
                for (int r = 0; r < 4; r++)
                    Cp[(size_t)(row + r) * ldc + col] = v[r];
            } else if constexpr (EPI == 4) {
                float* Cp = (float*)C;
#pragma unroll
                for (int r = 0; r < 4; r++) {
                    float s = 1.0f / (1.0f + __expf(-v[r]));
                    Cp[(size_t)(row + r) * ldc + col] = s;
                }
            }
        }
    }
}

// ---------------------------------------------------------------------------
// Fused-conversion BT-GEMM: A is f32 (adj), converted to bf16 during staging.
// Reg-staged A (issue loads early / cvt+ds_write late); B via global_load_lds.
// Side-stores bf16 A tiles to Aout when blockIdx.x==0 (exactly-once coverage).
// Epilogue = f32 partial at blockIdx.z*M*ldc (split-K).
// ---------------------------------------------------------------------------
template <int BM, int BN, int WM, int WN>
__launch_bounds__((BM / WM) * (BN / WN) * 64, 2)
__global__ void gemm_a32(const float* __restrict__ A32, int lda,
                         const u16* __restrict__ B, int ldb,
                         float* __restrict__ C, int ldc,
                         u16* __restrict__ Aout,
                         int M, int kLen) {
    constexpr int BK = 64;
    constexpr int NWCOL = BN / WN;
    constexpr int NWAVES = (BM / WM) * (BN / WN);
    constexpr int THREADS = NWAVES * 64;
    constexpr int MI = WM / 16, NI = WN / 16;
    constexpr int CPR = BK / 4;                          // f32x4 chunks per row
    constexpr int ACH = (BM * BK) / (THREADS * 4);       // chunks per thread
    constexpr int B_LOADS = (BN * BK * 2) / (THREADS * 16);

    __shared__ u16 Al[2][BM * BK];
    __shared__ u16 Bl[2][BN * BK];

    const int tid = threadIdx.x;
    const int m0 = blockIdx.y * BM;
    const int n0 = blockIdx.x * BN;
    const int kbase = blockIdx.z * kLen;

    const int l = tid & 63;
    const int w = tid >> 6;
    const int wr = w / NWCOL, wc = w % NWCOL;
    const int lr = l & 15, lk = l >> 4;

    const size_t ldbb = (size_t)ldb * 2;
    const float* Abase = A32 + (size_t)m0 * lda + kbase;
    const char* Bbase = (const char*)(B + (size_t)n0 * ldb + kbase);
    const bool side = (blockIdx.x == 0);

    f32x4 areg[ACH];

    auto issueA = [&](int kt) {
        const float* a = Abase + (size_t)kt * BK;
#pragma unroll
        for (int i = 0; i < ACH; i++) {
            int c = tid + i * THREADS;
            int row = c / CPR, col = (c % CPR) * 4;
            areg[i] = *(const f32x4*)(a + (size_t)row * lda + col);
        }
    };
    auto writeA = [&](int buf, int kt) {
#pragma unroll
        for (int i = 0; i < ACH; i++) {
            int c = tid + i * THREADS;
            int row = c / CPR, col = (c % CPR) * 4;
            u16x4 o;
            o[0] = f2bf(areg[i][0]); o[1] = f2bf(areg[i][1]);
            o[2] = f2bf(areg[i][2]); o[3] = f2bf(areg[i][3]);
            *(u16x4*)&Al[buf][row * BK + col] = o;
            if (side)
                *(u16x4*)(Aout + (size_t)(m0 + row) * lda + kbase + kt * BK + col) = o;
        }
    };
    auto stageB = [&](int buf, int kt) {
        const char* b = Bbase + (size_t)kt * (BK * 2);
#pragma unroll
        for (int i = 0; i < B_LOADS; i++) {
            int off = (tid + i * THREADS) * 16;
            gload16(b + (size_t)(off >> 7) * ldbb + (off & 127),
                    (char*)&Bl[buf][0] + off);
        }
    };

    f32x4 acc[MI][NI] = {};

    const int ksteps = kLen / BK;
    issueA(0);
    stageB(0, 0);
    writeA(0, 0);
    for (int kt = 0; kt < ksteps; ++kt) {
        const int cur = kt & 1;
        __syncthreads();   // buf[cur] staged (ds_write + gload_lds drained); buf[cur^1] readers done
        if (kt + 1 < ksteps) { issueA(kt + 1); stageB(cur ^ 1, kt + 1); }
#pragma unroll
        for (int ks = 0; ks < 2; ++ks) {
            short8 af[MI];
            short8 bf[NI];
#pragma unroll
            for (int mi = 0; mi < MI; ++mi)
                af[mi] = *(const short8*)&Al[cur][(wr * WM + mi * 16 + lr) * BK + ks * 32 + lk * 8];
#pragma unroll
            for (int ni = 0; ni < NI; ++ni)
                bf[ni] = *(const short8*)&Bl[cur][(wc * WN + ni * 16 + lr) * BK + ks * 32 + lk * 8];
#pragma unroll
            for (int mi = 0; mi < MI; ++mi)
#pragma unroll
                for (int ni = 0; ni < NI; ++ni)
                    acc[mi][ni] = __builtin_amdgcn_mfma_f32_16x16x32_bf16(
                        af[mi], bf[ni], acc[mi][ni], 0, 0, 0);
        }
        if (kt + 1 < ksteps) writeA(cur ^ 1, kt + 1);   // cvt + ds_write next A tile
    }

#pragma unroll
    for (int mi = 0; mi < MI; ++mi) {
#pragma unroll
        for (int ni = 0; ni < NI; ++ni) {
            const int row = m0 + wr * WM + mi * 16 + lk * 4;
            const int col = n0 + wc * WN + ni * 16 + lr;
            f32x4 v = acc[mi][ni];
            float* Cp = C + (size_t)blockIdx.z * M * ldc;
#pragma unroll
            for (int r = 0; r < 4; r++)
                Cp[(size_t)(row + r) * ldc + col] = v[r];
        }
    }
}

// ---------------------------------------------------------------------------
__global__ void cvt8(const float* __restrict__ in, u16* __restrict__ out, int n8) {
    int stride = gridDim.x * blockDim.x;
    for (int i = blockIdx.x * blockDim.x + threadIdx.x; i < n8; i += stride) {
        f32x4 a = ((const f32x4*)in)[2 * (size_t)i];
        f32x4 b = ((const f32x4*)in)[2 * (size_t)i + 1];
        ushort8 o;
        o[0] = f2bf(a[0]); o[1] = f2bf(a[1]); o[2] = f2bf(a[2]); o[3] = f2bf(a[3]);
        o[4] = f2bf(b[0]); o[5] = f2bf(b[1]); o[6] = f2bf(b[2]); o[7] = f2bf(b[3]);
        ((ushort8*)out)[i] = o;
    }
}

__global__ void trcvt(const float* __restrict__ in, u16* __restrict__ out, int R, int C) {
    int i = blockIdx.x * blockDim.x + threadIdx.x;
    if (i < R * C) {
        int r = i / C, c = i - r * C;
        out[(size_t)c * R + r] = f2bf(in[i]);
    }
}

// split-K reduce: out[i] = bf16( [relu]( sum_z p[z][i] + bias[i & colmask] ) )
template <int PARTS, bool RELU>
__global__ void reduce_add(const float* __restrict__ p, const float* __restrict__ bias,
                           u16* __restrict__ out, int n, int colmask) {
    int i = (blockIdx.x * blockDim.x + threadIdx.x) * 4;
    if (i >= n) return;
    f32x4 acc = *(const f32x4*)(p + i);
#pragma unroll
    for (int z = 1; z < PARTS; z++) {
        f32x4 q = *(const f32x4*)(p + (size_t)z * n + i);
        acc[0] += q[0]; acc[1] += q[1]; acc[2] += q[2]; acc[3] += q[3];
    }
    u16x4 o;
#pragma unroll
    for (int j = 0; j < 4; j++) {
        float v = acc[j] + bias[(i + j) & colmask];
        if constexpr (RELU) v = v > 0.f ? v : 0.f;
        o[j] = f2bf(v);
    }
    *(u16x4*)(out + i) = o;
}

// ---------------------------------------------------------------------------
extern "C" void kernel_launch(void* const* d_in, const int* in_sizes, int n_in,
                              void* d_out, int out_size, void* d_ws, size_t ws_size,
                              hipStream_t stream) {
    constexpr int N = 8192, F = 512, H = 256, CL = 64;

    const float* x   = (const float*)d_in[0];
    const float* adj = (const float*)d_in[1];
    const float* W1  = (const float*)d_in[2];
    const float* b1  = (const float*)d_in[3];
    const float* W2  = (const float*)d_in[4];
    const float* b2  = (const float*)d_in[5];
    float* out = (float*)d_out;

    // d_out carve (all dead before gemm5 overwrites the full 256 MiB)
    u16*   adjb = (u16*)d_out;                                        // 128 MiB
    float* Hp   = (float*)((char*)d_out + (size_t)128 * 1024 * 1024); // 32 MiB: [4][8192][256]
    float* Zp   = (float*)((char*)d_out + (size_t)160 * 1024 * 1024); // 16 MiB: [8][8192][64]

    // workspace carve-up (~18.3 MB total)
    u16* xb   = (u16*)d_ws;                       // [8192][512]
    u16* W1tb = xb   + (size_t)N * F;             // [256][512]
    u16* Y1tb = W1tb + (size_t)H * F;             // [256][8192]
    u16* Hb   = Y1tb + (size_t)H * N;             // [8192][256]
    u16* W2tb = Hb   + (size_t)N * H;             // [64][256]
    u16* Y2tb = W2tb + (size_t)CL * H;            // [64][8192]
    u16* Zb   = Y2tb + (size_t)CL * N;            // [8192][64]

    // small conversions
    cvt8<<<256, 256, 0, stream>>>(x, xb, N * F / 8);
    trcvt<<<(F * H + 255) / 256, 256, 0, stream>>>(W1, W1tb, F, H);
    trcvt<<<(H * CL + 255) / 256, 256, 0, stream>>>(W2, W2tb, H, CL);

    // gemm1: Y1t[h][m] = sum_k W1t[h][k] * x[m][k]   (M=256, N=8192, K=512)
    gemm_bt<64, 128, 32, 64, 0><<<dim3(N / 128, H / 64, 1), 256, 0, stream>>>(
        W1tb, F, xb, F, Y1tb, N, nullptr, H, N, F);

    // gemm2 (fused adj cvt, split-K=4):
    //   Hp[z][m][h] = sum_{k in quarter z} adj[m][k] * Y1t[h][k]
    //   side-stores adjb (bx==0 blocks cover all by x z tiles)
    gemm_a32<128, 128, 64, 64><<<dim3(H / 128, N / 128, 4), 256, 0, stream>>>(
        adj, N, Y1tb, N, Hp, H, adjb, N, N / 4);

    // Hb = bf16(relu(Hp0+..+Hp3 + b1))
    reduce_add<4, true><<<(N * H / 4 + 255) / 256, 256, 0, stream>>>(
        Hp, b1, Hb, N * H, H - 1);

    // gemm3: Y2t[c][m] = sum_k W2t[c][k] * H[m][k]   (M=64, N=8192, K=256)
    gemm_bt<64, 64, 32, 32, 0><<<dim3(N / 64, 1, 1), 256, 0, stream>>>(
        W2tb, H, Hb, H, Y2tb, N, nullptr, CL, N, H);

    // gemm4 (split-K=8): Zp[z][m][c] = sum_{k in eighth z} adjb[m][k] * Y2t[c][k]
    gemm_bt<128, 64, 64, 32, 3><<<dim3(1, N / 128, 8), 256, 0, stream>>>(
        adjb, N, Y2tb, N, Zp, CL, nullptr, N, CL, N / 8);

    // Zb = bf16(Zp0+..+Zp7 + b2)
    reduce_add<8, false><<<(N * CL / 4 + 255) / 256, 256, 0, stream>>>(
        Zp, b2, Zb, N * CL, CL - 1);

    // gemm5: out[i][j] = sigmoid(sum_k Zb[i][k] * Zb[j][k])  (M=N=8192, K=64)
    gemm_bt<128, 128, 64, 64, 4><<<dim3(N / 128, N / 128, 1), 256, 0, stream>>>(
        Zb, CL, Zb, CL, out, N, nullptr, N, N, CL);
}